// Round 9
// baseline (86.090 us; speedup 1.0000x reference)
//
#include <hip/hip_runtime.h>
#include <hip/hip_fp16.h>

typedef _Float16 f16;
typedef f16 f16x4 __attribute__((ext_vector_type(4)));
typedef f16 f16x8 __attribute__((ext_vector_type(8)));
typedef float f32x4 __attribute__((ext_vector_type(4)));

#define NN 1024

// workspace layout (bytes) — img2 IDENTICAL to rounds 5-8 (verified)
// img2: f16 [20][8192] — B-operand images in FRAGMENT-LINEAR order:
//   per (chunk c, half in {0,1}): 4096 f16 = [nt:4][ks:2][lane:64][8 f16],
//   element = B[n = half*64+nt*16+lm][k = ks*32+q*8+s], lane = q*16+lm.
//   chunks 0..15 : W0^T j-chunks; 16,17 : W1 k-halves; 18,19 : W2 k-halves
#define IMG2_OFF  0
#define W8_OFF    327680                 // f32 [128] : W0[8][:] (norm row)
#define BIAS0_OFF 328192                 // f32 [32][128] : b0 + u[b] @ W0[0:8]

__global__ __launch_bounds__(256) void prep_kernel(
    const float* __restrict__ u,  const float* __restrict__ W0,
    const float* __restrict__ b0, const float* __restrict__ W1,
    const float* __restrict__ W2,
    f16* __restrict__ img2, float* __restrict__ w8v, float* __restrict__ bias0,
    float* __restrict__ outp)
{
    const int t = threadIdx.x;
    const int blk = blockIdx.x;
    if (blk < 160) {
        int flat = blk * 1024 + t * 4;
        int c   = flat >> 13;
        int rem = flat & 8191;
        int s0  = rem & 7;              // 0 or 4
        int lm  = (rem >> 3) & 15;
        int q   = (rem >> 7) & 3;
        int ks  = (rem >> 9) & 1;
        int nt  = (rem >> 10) & 3;
        int wn  = (rem >> 12) & 1;
        int n = wn * 64 + nt * 16 + lm;
        f16x4 v;
#pragma unroll
        for (int e = 0; e < 4; ++e) {
            int k = ks * 32 + q * 8 + s0 + e;
            float val;
            if (c < 16)       val = W0[(9 + c * 64 + k) * 128 + n];
            else if (c < 18)  val = W1[((c - 16) * 64 + k) * 128 + n];
            else              val = W2[((c - 18) * 64 + k) * 128 + n];
            v[e] = (f16)val;
        }
        *(f16x4*)&img2[flat] = v;
    } else if (blk < 176) {
        int idx = (blk - 160) * 256 + t;
        int b = idx >> 7, h = idx & 127;
        float s = b0[h];
#pragma unroll
        for (int g = 0; g < 8; ++g) s += u[b * 8 + g] * W0[g * 128 + h];
        bias0[idx] = s;
    } else if (blk == 176) {
        if (t < 128) w8v[t] = W0[8 * 128 + t];
    } else {
        int idx = (blk - 177) * 1024 + t * 4;
        if (idx < 12288) { float4 z = {0.f, 0.f, 0.f, 0.f}; *(float4*)&outp[idx] = z; }
    }
}

// Block = 64 i-rows x 128 h; 8 waves of 64; wave tile = 64 i x 16 h.
// B direct from L2 (one chunk ahead in registers); grid 512 -> 2 blocks/CU,
// 16 waves/CU (2x round 8). B-traffic unchanged at 160 MB (no duplication).
__global__ __launch_bounds__(512, 4) void fused_kernel(
    const float* __restrict__ x, const float* __restrict__ b1p,
    const float* __restrict__ b2p, const f16* __restrict__ img2,
    const float* __restrict__ w8v, const float* __restrict__ bias0,
    float* __restrict__ outp)
{
    // 26.8 KB LDS -> 2 blocks/CU
    __shared__ __align__(16) f16 Dsh[2][64 * 64];   // 16 KB D dbuf; later Hh[64][128]
    __shared__ __align__(16) f16 xjsh[1024 * 4];    // 8 KB: all x rows f16, [3]=0
    __shared__ __align__(16) float xi[64 * 4];
    __shared__ float normv[64];
    __shared__ float biass[128];
    __shared__ float w8s[128];

    const int t = threadIdx.x;
    const int b = blockIdx.x >> 4;
    const int i0 = (blockIdx.x & 15) * 64;

    const int lane = t & 63, wv = t >> 6;   // wv 0..7
    const int lm = lane & 15, q = lane >> 4;
    const int half = wv >> 2;               // img2 64-h half
    const int ntw  = wv & 3;                // nt inside the half
    const int jg   = wv & 3;                // dotstore j-group
    const int ih   = wv >> 2;               // dotstore i-half
    f16* Hh = &Dsh[0][0];                   // 64 x 128 swizzled h0/h1 (16 KB)

    // ---- stage xjsh (first 256 threads; 4 rows each as f16x4, w=0) ----
    if (t < 256) {
        const float* xb = x + (size_t)b * NN * 3;
        float4 v0 = *(const float4*)(xb + t * 12);
        float4 v1 = *(const float4*)(xb + t * 12 + 4);
        float4 v2 = *(const float4*)(xb + t * 12 + 8);
        f16x4 r0; r0[0] = (f16)v0.x; r0[1] = (f16)v0.y; r0[2] = (f16)v0.z; r0[3] = (f16)0;
        f16x4 r1; r1[0] = (f16)v0.w; r1[1] = (f16)v1.x; r1[2] = (f16)v1.y; r1[3] = (f16)0;
        f16x4 r2; r2[0] = (f16)v1.z; r2[1] = (f16)v1.w; r2[2] = (f16)v2.x; r2[3] = (f16)0;
        f16x4 r3; r3[0] = (f16)v2.y; r3[1] = (f16)v2.z; r3[2] = (f16)v2.w; r3[3] = (f16)0;
        *(f16x4*)&xjsh[(t * 4 + 0) * 4] = r0;
        *(f16x4*)&xjsh[(t * 4 + 1) * 4] = r1;
        *(f16x4*)&xjsh[(t * 4 + 2) * 4] = r2;
        *(f16x4*)&xjsh[(t * 4 + 3) * 4] = r3;
    } else if (t < 448) {
        int u2 = t - 256;                    // 0..191
        int i = u2 / 3, d = u2 - i * 3;
        xi[i * 4 + d] = x[(size_t)(b * NN + i0 + i) * 3 + d];
    } else {
        // t 448..511: none
    }
    if (t >= 256 && t < 384) { int h = t - 256; biass[h] = bias0[b * 128 + h]; w8s[h] = w8v[h]; }
    __syncthreads();
    if (t < 64) {
        float a0 = xi[t * 4], a1 = xi[t * 4 + 1], a2 = xi[t * 4 + 2];
        normv[t] = __builtin_amdgcn_sqrtf(a0 * a0 + a1 * a1 + a2 * a2);
    }

    // xi B-fragments for dot-MFMA (16x16x16, layout verified R1-R8):
    // this wave covers it = ih*2 + itl (i rows ih*32 .. ih*32+31)
    f16x4 bi[2];
#pragma unroll
    for (int itl = 0; itl < 2; ++itl) {
        f16x4 v; v[0] = (f16)0; v[1] = (f16)0; v[2] = (f16)0; v[3] = (f16)0;
        if (q == 0) {
            int ii = (ih * 2 + itl) * 16 + lm;
            v[0] = (f16)xi[ii * 4];
            v[1] = (f16)xi[ii * 4 + 1];
            v[2] = (f16)xi[ii * 4 + 2];
        }
        bi[itl] = v;
    }

    // dot-MFMA for chunk jc -> sqrt -> b64 stores into Dsh[buf]
    // lane holds D[j = jg*16+q*4+r][i = (ih*2+itl)*16+lm]
    auto dotstore = [&](int jc, int buf) {
        f16x4 ajv; ajv[0] = (f16)0; ajv[1] = (f16)0; ajv[2] = (f16)0; ajv[3] = (f16)0;
        if (q == 0)
            ajv = *(const f16x4*)&xjsh[(jc * 64 + jg * 16 + lm) * 4];
#pragma unroll
        for (int itl = 0; itl < 2; ++itl) {
            f32x4 z; z[0] = 0.f; z[1] = 0.f; z[2] = 0.f; z[3] = 0.f;
            f32x4 cg = __builtin_amdgcn_mfma_f32_16x16x16f16(ajv, bi[itl], z, 0, 0, 0);
            f16x4 dv;
#pragma unroll
            for (int r = 0; r < 4; ++r)
                dv[r] = (f16)__builtin_amdgcn_sqrtf(fmaxf(cg[r], 0.f));
            int row = (ih * 2 + itl) * 16 + lm;
            int colstart = jg * 16 + q * 4;
            int addr = row * 64 + (((colstart & ~7) ^ ((row & 7) << 3)) | (colstart & 7));
            *(f16x4*)&Dsh[buf][addr] = dv;
        }
    };

    f32x4 acc[4];   // [mt] : 64 i x 16 h
    auto zero_acc = [&]() {
#pragma unroll
        for (int mt = 0; mt < 4; ++mt)
#pragma unroll
            for (int e = 0; e < 4; ++e) acc[mt][e] = 0.f;
    };
    zero_acc();

    // ---- prologue: D chunk 0 + B chunk 0 prefetch ----
    f16x8 bfbuf[2][2];   // [parity][ks]
    {
        const f16* wb = img2 + (size_t)(0 * 2 + half) * 4096 + lane * 8;
#pragma unroll
        for (int ks = 0; ks < 2; ++ks)
            bfbuf[0][ks] = *(const f16x8*)(wb + (ntw * 2 + ks) * 512);
    }
    dotstore(0, 0);
    __syncthreads();

    // ---- layer-0 K-loop: B consumed one full iteration after issue ----
#pragma unroll
    for (int jc = 0; jc < 16; ++jc) {
        const int cur = jc & 1, nxt = cur ^ 1;
        if (jc < 15) {
            const f16* wb = img2 + (size_t)((jc + 1) * 2 + half) * 4096 + lane * 8;
#pragma unroll
            for (int ks = 0; ks < 2; ++ks)
                bfbuf[nxt][ks] = *(const f16x8*)(wb + (ntw * 2 + ks) * 512);
        }
        f16x8 af[4][2];
#pragma unroll
        for (int mt = 0; mt < 4; ++mt)
#pragma unroll
            for (int ks = 0; ks < 2; ++ks) {
                int row = mt * 16 + lm;
                int col = ks * 32 + q * 8;
                af[mt][ks] = *(const f16x8*)(Dsh[cur] + row * 64 + (col ^ ((row & 7) << 3)));
            }
        if (jc < 15) dotstore(jc + 1, nxt);
#pragma unroll
        for (int ks = 0; ks < 2; ++ks)
#pragma unroll
            for (int mt = 0; mt < 4; ++mt)
                acc[mt] = __builtin_amdgcn_mfma_f32_16x16x32_f16(
                    af[mt][ks], bfbuf[cur][ks], acc[mt], 0, 0, 0);
        __syncthreads();
    }

    // hoist layer-1 B loads (chunks 16,17): k = ks*32+q*8+s, ks 0..3
    f16x8 bL[4];
#pragma unroll
    for (int ks = 0; ks < 4; ++ks) {
        const f16* wb = img2 + (size_t)((16 + (ks >> 1)) * 2 + half) * 4096 + lane * 8;
        bL[ks] = *(const f16x8*)(wb + (ntw * 2 + (ks & 1)) * 512);
    }

    // ---- epilogue 0: h0 = leaky(acc + bias + norm*w8) -> Hh[64][128] swizzled ----
    // lane holds C[i = mt*16+q*4+r][h = wv*16 + lm]
    const int hw = wv * 16 + lm;
#pragma unroll
    for (int mt = 0; mt < 4; ++mt) {
        const float bh = biass[hw], w8h = w8s[hw];
#pragma unroll
        for (int r = 0; r < 4; ++r) {
            int i = mt * 16 + q * 4 + r;
            float val = acc[mt][r] + bh + normv[i] * w8h;
            val = val > 0.f ? val : 0.01f * val;
            int addr = i * 128 + (((hw & ~7) ^ ((i & 7) << 3)) | (hw & 7));
            Hh[addr] = (f16)val;
        }
    }
    __syncthreads();

    // ---- layer 1: A = h0 rows from Hh (K=128), B = bL ----
    zero_acc();
#pragma unroll
    for (int ks = 0; ks < 4; ++ks) {
        f16x8 af[4];
#pragma unroll
        for (int mt = 0; mt < 4; ++mt) {
            int row = mt * 16 + lm;
            int col = ks * 32 + q * 8;
            af[mt] = *(const f16x8*)(Hh + row * 128 + (col ^ ((row & 7) << 3)));
        }
#pragma unroll
        for (int mt = 0; mt < 4; ++mt)
            acc[mt] = __builtin_amdgcn_mfma_f32_16x16x32_f16(
                af[mt], bL[ks], acc[mt], 0, 0, 0);
    }

    // hoist layer-2 B loads (chunks 18,19)
    f16x8 bM[4];
#pragma unroll
    for (int ks = 0; ks < 4; ++ks) {
        const f16* wb = img2 + (size_t)((18 + (ks >> 1)) * 2 + half) * 4096 + lane * 8;
        bM[ks] = *(const f16x8*)(wb + (ntw * 2 + (ks & 1)) * 512);
    }
    __syncthreads();

    // ---- epilogue 1: h1 = leaky(acc + b1) -> Hh ----
#pragma unroll
    for (int mt = 0; mt < 4; ++mt) {
        const float bh = b1p[hw];
#pragma unroll
        for (int r = 0; r < 4; ++r) {
            int i = mt * 16 + q * 4 + r;
            float val = acc[mt][r] + bh;
            val = val > 0.f ? val : 0.01f * val;
            int addr = i * 128 + (((hw & ~7) ^ ((i & 7) << 3)) | (hw & 7));
            Hh[addr] = (f16)val;
        }
    }
    __syncthreads();

    // ---- layer 2 ----
    zero_acc();
#pragma unroll
    for (int ks = 0; ks < 4; ++ks) {
        f16x8 af[4];
#pragma unroll
        for (int mt = 0; mt < 4; ++mt) {
            int row = mt * 16 + lm;
            int col = ks * 32 + q * 8;
            af[mt] = *(const f16x8*)(Hh + row * 128 + (col ^ ((row & 7) << 3)));
        }
#pragma unroll
        for (int mt = 0; mt < 4; ++mt)
            acc[mt] = __builtin_amdgcn_mfma_f32_16x16x32_f16(
                af[mt], bM[ks], acc[mt], 0, 0, 0);
    }

    // ---- contraction: out[b,o,d] += sum_i (fk+b2)*x_i / N ----
    float p[3];
    p[0] = 0.f; p[1] = 0.f; p[2] = 0.f;
    const float bo = b2p[hw];
#pragma unroll
    for (int mt = 0; mt < 4; ++mt)
#pragma unroll
        for (int r = 0; r < 4; ++r) {
            int i = mt * 16 + q * 4 + r;
            float x0 = xi[i * 4], x1 = xi[i * 4 + 1], x2 = xi[i * 4 + 2];
            float fkv = acc[mt][r] + bo;
            p[0] = fmaf(fkv, x0, p[0]);
            p[1] = fmaf(fkv, x1, p[1]);
            p[2] = fmaf(fkv, x2, p[2]);
        }
#pragma unroll
    for (int d = 0; d < 3; ++d) {
        float s = p[d];
        s += __shfl_xor(s, 16);
        s += __shfl_xor(s, 32);
        if (q == 0)
            atomicAdd(&outp[(b * 128 + hw) * 3 + d], s * (1.0f / 1024.0f));
    }
}

extern "C" void kernel_launch(void* const* d_in, const int* in_sizes, int n_in,
                              void* d_out, int out_size, void* d_ws, size_t ws_size,
                              hipStream_t stream) {
    const float* x  = (const float*)d_in[0];
    const float* u  = (const float*)d_in[1];
    const float* W0 = (const float*)d_in[2];
    const float* b0 = (const float*)d_in[3];
    const float* W1 = (const float*)d_in[4];
    const float* b1 = (const float*)d_in[5];
    const float* W2 = (const float*)d_in[6];
    const float* b2 = (const float*)d_in[7];

    char* ws = (char*)d_ws;
    f16*   img2  = (f16*)(ws + IMG2_OFF);
    float* w8v   = (float*)(ws + W8_OFF);
    float* bias0 = (float*)(ws + BIAS0_OFF);
    float* out   = (float*)d_out;

    prep_kernel<<<189, 256, 0, stream>>>(u, W0, b0, W1, W2, img2, w8v, bias0, out);
    fused_kernel<<<512, 512, 0, stream>>>(x, b1, b2, img2, w8v, bias0, out);
}